// Round 14
// baseline (5584.027 us; speedup 1.0000x reference)
//
#include <hip/hip_runtime.h>
#include <stdint.h>

#define NB 64
#define NS 512
#define NI 512
#define NH 512

typedef __attribute__((ext_vector_type(8))) short bf16x8;
typedef __attribute__((ext_vector_type(4))) float f32x4;

__device__ __forceinline__ unsigned short f2bf(float f) {
  unsigned u = __float_as_uint(f);
  return (unsigned short)((u + 0x7fffu + ((u >> 16) & 1u)) >> 16);
}
__device__ __forceinline__ float bf2f(unsigned short h) {
  return __uint_as_float(((unsigned)h) << 16);
}
__device__ __forceinline__ float sigm(float x) { return 1.0f / (1.0f + __expf(-x)); }
__device__ __forceinline__ float tanh_f(float x) {
  float e = __expf(-2.0f * fabsf(x));
  return copysignf((1.0f - e) / (1.0f + e), x);
}

// ws layout (u32 units):
//  [0,16):    epoch[8 groups][2 planes] — monotone counters; plane p of group g
//             reaches 32*t once all 32 slice-producers of plane p published h(t-1)
//  [1024,+):  x_bf16 as u16[64][512][512]
#define EPOCH_OFF 0
#define XBF_OFF 1024
#define WS_BYTES_NEEDED ((size_t)XBF_OFF * 4 + (size_t)NB * NS * NI * 2)

__global__ __launch_bounds__(256) void k_xconv(const float* __restrict__ x,
                                               unsigned short* __restrict__ xb) {
  size_t i = ((size_t)blockIdx.x * 256 + threadIdx.x) * 4;
  float4 v = *(const float4*)(x + i);
  ushort4 o;
  o.x = f2bf(v.x); o.y = f2bf(v.y); o.z = f2bf(v.z); o.w = f2bf(v.w);
  *(ushort4*)(xb + i) = o;
}

__global__ __launch_bounds__(256) void k_init(unsigned int* __restrict__ ws) {
  int idx = blockIdx.x * 256 + threadIdx.x;
  if (idx < 16) ws[EPOCH_OFF + idx] = 0u;  // replay-safe reset
}

// Persistent cooperative LSTM. grid 256 WGs x 512 thr. (R9 structure verbatim;
// only change: per-plane epoch counters replace the 64-flag array.)
// Group g = bid&7: 8 batches [g*8,+8). Slice s = bid>>3: h-cols [s*16,+16),
// all 4 gates. Wave w = K-eighth (cols [w*64,+64)).
// Exchange: reducer waves 0,1 publish fp32 h into `out` via sc1 store + vmcnt
// ack, then lane0 atomicAdd(+1) to epoch[g][w] (device-scope, fire-and-forget).
// Loader waves 6,7 poll ONE epoch counter each (>= 32*t; 64-lane same-address
// load = 1 broadcast transaction), then stage 4 out-rows each via CACHED
// global_load_lds (per-step-unique addresses -> no stale-line hazard; L2-
// deduped across the group's 32 WGs). t=0 stages from h0, no poll.
// WAR on hexL/part: rewritten only after S1(t+1)/flag-gated DMA whose epoch
// target requires this WG's reducers to have read part(t). Deadlock-free:
// epoch(t+1) adds depend only on own-WG S2(t).
__global__ __launch_bounds__(512, 2) void k_lstm(
    const float* __restrict__ Wih, const float* __restrict__ bih,
    const float* __restrict__ Whh, const float* __restrict__ bhh,
    const float* __restrict__ h0, const float* __restrict__ c0,
    float* __restrict__ out, unsigned int* __restrict__ ws) {
  const int tid = threadIdx.x;
  const int lane = tid & 63;
  const int w = tid >> 6;   // K-eighth
  const int q = lane >> 4;
  const int c = lane & 15;
  const int b8 = lane & 7;  // A-frag batch (rows 8-15 duplicate 0-7)
  const int k0 = w * 64;
  const int g = blockIdx.x & 7;
  const int s = blockIdx.x >> 3;

  unsigned int* epochG = ws + EPOCH_OFF + g * 2;  // [2 planes]
  const unsigned short* xb = (const unsigned short*)(ws + XBF_OFF);

  // ---- weight fragments (hi/lo bf16 split): 4 gates x 2 K-chunks ----
  bf16x8 wih_hi[4][2], wih_lo[4][2], whh_hi[4][2], whh_lo[4][2];
#pragma unroll
  for (int g4 = 0; g4 < 4; ++g4) {
    const int wrow = g4 * 512 + s * 16 + c;  // B-frag col = c
#pragma unroll
    for (int kc = 0; kc < 2; ++kc) {
      const int kb = k0 + kc * 32 + q * 8;
      const float* pi = Wih + (size_t)wrow * NI + kb;
      const float* ph = Whh + (size_t)wrow * NH + kb;
      float4 i0 = *(const float4*)pi, i1 = *(const float4*)(pi + 4);
      float4 h0v = *(const float4*)ph, h1v = *(const float4*)(ph + 4);
      float vi[8] = {i0.x, i0.y, i0.z, i0.w, i1.x, i1.y, i1.z, i1.w};
      float vh[8] = {h0v.x, h0v.y, h0v.z, h0v.w, h1v.x, h1v.y, h1v.z, h1v.w};
#pragma unroll
      for (int r = 0; r < 8; ++r) {
        unsigned short a = f2bf(vi[r]);
        wih_hi[g4][kc][r] = (short)a;
        wih_lo[g4][kc][r] = (short)f2bf(vi[r] - bf2f(a));
        unsigned short b = f2bf(vh[r]);
        whh_hi[g4][kc][r] = (short)b;
        whh_lo[g4][kc][r] = (short)f2bf(vh[r] - bf2f(b));
      }
    }
  }

  // reducer mapping (waves 0,1): lane -> (batch bgc = g*8 + w*4 + q, col jg)
  const int bgc = g * 8 + ((w * 4 + q) & 7);  // clamped for non-reducer waves
  const int jg = s * 16 + c;
  const float bI = bih[jg] + bhh[jg];
  const float bF = bih[512 + jg] + bhh[512 + jg];
  const float bG = bih[1024 + jg] + bhh[1024 + jg];
  const float bO = bih[1536 + jg] + bhh[1536 + jg];
  float cst = c0[(size_t)bgc * NH + jg];

  __shared__ float hexL[8][516];       // staged h_{t-1} (fp32), 8 batches x 512
  __shared__ float part[4][8][4][72];  // [gate][wave][reg][col(+pad)]

  const unsigned short* xrow = xb + (size_t)(g * 8 + b8) * NS * NI + k0 + q * 8;
  bf16x8 xf0 = *(const bf16x8*)(xrow);
  bf16x8 xf1 = *(const bf16x8*)(xrow + 32);

#pragma unroll 1
  for (int t = 0; t < NS; ++t) {
    // ---- loader waves 6,7: poll plane epoch + stage h_{t-1} ----
    if (w >= 6) {
      const int lh = w - 6;  // stages batches [lh*4, lh*4+4) (plane lh)
      if (t > 0) {
        const unsigned tgt = (unsigned)(32 * t);
        const unsigned* ep = epochG + lh;
        unsigned ev = __hip_atomic_load(ep, __ATOMIC_RELAXED, __HIP_MEMORY_SCOPE_AGENT);
        while (!__all((int)(ev >= tgt)))
          ev = __hip_atomic_load(ep, __ATOMIC_RELAXED, __HIP_MEMORY_SCOPE_AGENT);
        asm volatile("" ::: "memory");  // keep DMA below the poll
      }
#pragma unroll
      for (int r4 = 0; r4 < 4; ++r4) {
        const int bl = lh * 4 + r4;
        const float* srow = (t == 0)
            ? (h0 + (size_t)(g * 8 + bl) * NH)
            : (out + ((size_t)(g * 8 + bl) * NS + (t - 1)) * NH);
        __builtin_amdgcn_global_load_lds(
            (const __attribute__((address_space(1))) unsigned*)(srow + lane * 4),
            (__attribute__((address_space(3))) unsigned*)&hexL[bl][0], 16, 0, 0);
        __builtin_amdgcn_global_load_lds(
            (const __attribute__((address_space(1))) unsigned*)(srow + 256 + lane * 4),
            (__attribute__((address_space(3))) unsigned*)&hexL[bl][256], 16, 0, 0);
      }
    }

    // ---- x-path MFMA (all waves; loaders' overlaps their DMA round trip) ----
    f32x4 acc[4];
#pragma unroll
    for (int g4 = 0; g4 < 4; ++g4) acc[g4] = (f32x4){0.f, 0.f, 0.f, 0.f};
#pragma unroll
    for (int g4 = 0; g4 < 4; ++g4) {
      acc[g4] = __builtin_amdgcn_mfma_f32_16x16x32_bf16(xf0, wih_hi[g4][0], acc[g4], 0, 0, 0);
      acc[g4] = __builtin_amdgcn_mfma_f32_16x16x32_bf16(xf0, wih_lo[g4][0], acc[g4], 0, 0, 0);
      acc[g4] = __builtin_amdgcn_mfma_f32_16x16x32_bf16(xf1, wih_hi[g4][1], acc[g4], 0, 0, 0);
      acc[g4] = __builtin_amdgcn_mfma_f32_16x16x32_bf16(xf1, wih_lo[g4][1], acc[g4], 0, 0, 0);
    }
    if (w >= 6) asm volatile("s_waitcnt vmcnt(0)" ::: "memory");  // DMA landed
    __builtin_amdgcn_s_barrier();  // S1: h staged
    asm volatile("" ::: "memory");

    // ---- h-path: fp32 from LDS -> hi/lo bf16 -> 3-term MFMA ----
#pragma unroll
    for (int kc = 0; kc < 2; ++kc) {
      const float* hp = &hexL[b8][k0 + kc * 32 + q * 8];
      float4 A = *(const float4*)hp;
      float4 B = *(const float4*)(hp + 4);
      float hv8[8] = {A.x, A.y, A.z, A.w, B.x, B.y, B.z, B.w};
      bf16x8 hh, hl;
#pragma unroll
      for (int r = 0; r < 8; ++r) {
        unsigned short a = f2bf(hv8[r]);
        hh[r] = (short)a;
        hl[r] = (short)f2bf(hv8[r] - bf2f(a));
      }
#pragma unroll
      for (int g4 = 0; g4 < 4; ++g4) {
        acc[g4] = __builtin_amdgcn_mfma_f32_16x16x32_bf16(hh, whh_hi[g4][kc], acc[g4], 0, 0, 0);
        acc[g4] = __builtin_amdgcn_mfma_f32_16x16x32_bf16(hl, whh_hi[g4][kc], acc[g4], 0, 0, 0);
        acc[g4] = __builtin_amdgcn_mfma_f32_16x16x32_bf16(hh, whh_lo[g4][kc], acc[g4], 0, 0, 0);
      }
    }

#pragma unroll
    for (int g4 = 0; g4 < 4; ++g4)
#pragma unroll
      for (int r = 0; r < 4; ++r) part[g4][w][r][lane] = acc[g4][r];

    asm volatile("s_waitcnt lgkmcnt(0)" ::: "memory");
    __builtin_amdgcn_s_barrier();  // S2: part visible
    asm volatile("" ::: "memory");
    // WAR safety: hexL/part rewritten at t+1 only after loaders pass their
    // epoch gate (own-plane epoch requires reducers below to have read part).

    const int tn = (t + 1 < NS) ? t + 1 : t;
    if (w < 2) {  // reducers: lane owns (b = w*4+q, j = c)
      float sI = bI, sF = bF, sG = bG, sO = bO;
      const int cidx = c + w * 16;
#pragma unroll
      for (int ww = 0; ww < 8; ++ww) {
        sI += part[0][ww][q][cidx];
        sF += part[1][ww][q][cidx];
        sG += part[2][ww][q][cidx];
        sO += part[3][ww][q][cidx];
      }
      float cn = sigm(sF) * cst + sigm(sI) * tanh_f(sG);
      cst = cn;
      float hv = sigm(sO) * tanh_f(cn);

      // publish: sc1 store of hv into out (the output store IS the exchange)
      unsigned* dst = (unsigned*)out + ((size_t)bgc * NS + t) * NH + jg;
      __hip_atomic_store(dst, __float_as_uint(hv), __ATOMIC_RELAXED, __HIP_MEMORY_SCOPE_AGENT);
      asm volatile("s_waitcnt vmcnt(0)" ::: "memory");  // data at coherence point
      if (lane == 0) atomicAdd(epochG + w, 1u);  // fire-and-forget epoch bump

      if (t == NS - 1) {  // final h/c tail (plain; flushed at kernel end)
        size_t hoff = (size_t)NB * NS * NH;
        out[hoff + (size_t)bgc * NH + jg] = hv;
        out[hoff + (size_t)NB * NH + (size_t)bgc * NH + jg] = cn;
      }
    }
    // x prefetch for t+1 (in flight across next S1 wait)
    xf0 = *(const bf16x8*)(xrow + (size_t)tn * NI);
    xf1 = *(const bf16x8*)(xrow + (size_t)tn * NI + 32);
  }
}

extern "C" void kernel_launch(void* const* d_in, const int* in_sizes, int n_in,
                              void* d_out, int out_size, void* d_ws, size_t ws_size,
                              hipStream_t stream) {
  if (ws_size < WS_BYTES_NEEDED) return;  // fail visibly rather than corrupt

  const float* x   = (const float*)d_in[0];
  const float* h0  = (const float*)d_in[1];
  const float* c0  = (const float*)d_in[2];
  const float* Wih = (const float*)d_in[3];
  const float* bih = (const float*)d_in[4];
  const float* Whh = (const float*)d_in[5];
  const float* bhh = (const float*)d_in[6];
  float* out = (float*)d_out;
  unsigned int* ws = (unsigned int*)d_ws;
  unsigned short* xbptr = (unsigned short*)(ws + XBF_OFF);

  k_xconv<<<dim3(16384), dim3(256), 0, stream>>>(x, xbptr);
  k_init<<<dim3(1), dim3(256), 0, stream>>>(ws);

  void* args[] = {(void*)&Wih, (void*)&bih, (void*)&Whh, (void*)&bhh,
                  (void*)&h0,  (void*)&c0,  (void*)&out, (void*)&ws};
  hipLaunchCooperativeKernel((const void*)k_lstm, dim3(256), dim3(512), args, 0, stream);
}

// Round 15
// 1720.969 us; speedup vs baseline: 3.2447x; 3.2447x over previous
//
#include <hip/hip_runtime.h>
#include <stdint.h>

#define NB 64
#define NS 512
#define NI 512
#define NH 512

typedef __attribute__((ext_vector_type(8))) short bf16x8;
typedef __attribute__((ext_vector_type(4))) float f32x4;

__device__ __forceinline__ unsigned short f2bf(float f) {
  unsigned u = __float_as_uint(f);
  return (unsigned short)((u + 0x7fffu + ((u >> 16) & 1u)) >> 16);
}
__device__ __forceinline__ float bf2f(unsigned short h) {
  return __uint_as_float(((unsigned)h) << 16);
}
__device__ __forceinline__ float sigm(float x) { return 1.0f / (1.0f + __expf(-x)); }
__device__ __forceinline__ float tanh_f(float x) {
  float e = __expf(-2.0f * fabsf(x));
  return copysignf((1.0f - e) / (1.0f + e), x);
}

// ws layout (u32 units):
//  [0,512):   flags[8 groups][2 red-waves][32 slices] = steps published (monotonic)
//  [1024,+):  x_bf16 as u16[64][512][512]
#define FLAGS_OFF 0
#define XBF_OFF 1024
#define WS_BYTES_NEEDED ((size_t)XBF_OFF * 4 + (size_t)NB * NS * NI * 2)

__global__ __launch_bounds__(256) void k_xconv(const float* __restrict__ x,
                                               unsigned short* __restrict__ xb) {
  size_t i = ((size_t)blockIdx.x * 256 + threadIdx.x) * 4;
  float4 v = *(const float4*)(x + i);
  ushort4 o;
  o.x = f2bf(v.x); o.y = f2bf(v.y); o.z = f2bf(v.z); o.w = f2bf(v.w);
  *(ushort4*)(xb + i) = o;
}

__global__ __launch_bounds__(256) void k_init(unsigned int* __restrict__ ws) {
  int idx = blockIdx.x * 256 + threadIdx.x;
  if (idx < 512) ws[FLAGS_OFF + idx] = 0u;  // no steps published yet
}

// Persistent cooperative LSTM. grid 256 WGs x 512 thr.  (R9, measured best)
// Group g = bid&7: 8 batches [g*8, g*8+8). Slice s = bid>>3: h-cols [s*16,+16),
// all 4 gates. Wave w = K-eighth (64 K-cols); 4 gate-tile 16x16 MFMA accs
// (A rows 8-15 duplicate batches 0-7; duplicates ignored in the reduction).
//
// h exchange THROUGH `out` (per-step-unique addresses -> no stale-cache hazard,
// no fences, no backpressure):
//   producers (waves 0,1): sc1 u32 store of fp32 hv to out[b][t][j]  (the store
//     we owe anyway) + vmcnt ack + sc1 flag (proven primitives only).
//   consumers (loader waves 6,7): poll 32 flags each (sc1 atomic loads), then
//     stage 4 out-rows each (8KB) via CACHED global_load_lds -> L2-deduped
//     across the 32 same-group WGs. t=0 stages from the h0 input instead.
// Consumers split fp32 h -> bf16 hi/lo in-register.
__global__ __launch_bounds__(512, 2) void k_lstm(
    const float* __restrict__ Wih, const float* __restrict__ bih,
    const float* __restrict__ Whh, const float* __restrict__ bhh,
    const float* __restrict__ h0, const float* __restrict__ c0,
    float* __restrict__ out, unsigned int* __restrict__ ws) {
  const int tid = threadIdx.x;
  const int lane = tid & 63;
  const int w = tid >> 6;   // K-eighth
  const int q = lane >> 4;
  const int c = lane & 15;
  const int b8 = lane & 7;  // A-frag batch (rows 8-15 duplicate 0-7)
  const int k0 = w * 64;
  const int g = blockIdx.x & 7;
  const int s = blockIdx.x >> 3;

  unsigned int* flagsG = ws + FLAGS_OFF + g * 64;  // [2 red-waves][32 slices]
  const unsigned short* xb = (const unsigned short*)(ws + XBF_OFF);

  // ---- weight fragments (hi/lo bf16 split): 4 gates x 2 K-chunks ----
  // B-frag: col = c -> gate row wrow; k = q*8 + r within chunk.
  bf16x8 wih_hi[4][2], wih_lo[4][2], whh_hi[4][2], whh_lo[4][2];
#pragma unroll
  for (int g4 = 0; g4 < 4; ++g4) {
    const int wrow = g4 * 512 + s * 16 + c;
#pragma unroll
    for (int kc = 0; kc < 2; ++kc) {
      const int kb = k0 + kc * 32 + q * 8;
      const float* pi = Wih + (size_t)wrow * NI + kb;
      const float* ph = Whh + (size_t)wrow * NH + kb;
      float4 i0 = *(const float4*)pi, i1 = *(const float4*)(pi + 4);
      float4 h0v = *(const float4*)ph, h1v = *(const float4*)(ph + 4);
      float vi[8] = {i0.x, i0.y, i0.z, i0.w, i1.x, i1.y, i1.z, i1.w};
      float vh[8] = {h0v.x, h0v.y, h0v.z, h0v.w, h1v.x, h1v.y, h1v.z, h1v.w};
#pragma unroll
      for (int r = 0; r < 8; ++r) {
        unsigned short a = f2bf(vi[r]);
        wih_hi[g4][kc][r] = (short)a;
        wih_lo[g4][kc][r] = (short)f2bf(vi[r] - bf2f(a));
        unsigned short b = f2bf(vh[r]);
        whh_hi[g4][kc][r] = (short)b;
        whh_lo[g4][kc][r] = (short)f2bf(vh[r] - bf2f(b));
      }
    }
  }

  // reducer mapping (waves 0,1): lane -> (batch bgc = g*8 + w*4 + q, col jg)
  const int bgc = g * 8 + ((w * 4 + q) & 7);  // clamped for non-reducer waves
  const int jg = s * 16 + c;
  const float bI = bih[jg] + bhh[jg];
  const float bF = bih[512 + jg] + bhh[512 + jg];
  const float bG = bih[1024 + jg] + bhh[1024 + jg];
  const float bO = bih[1536 + jg] + bhh[1536 + jg];
  float cst = c0[(size_t)bgc * NH + jg];

  __shared__ float hexL[8][516];       // staged h_{t-1} (fp32), 8 batches x 512
  __shared__ float part[4][8][4][72];  // [gate][wave][reg][col]

  const unsigned short* xrow = xb + (size_t)(g * 8 + b8) * NS * NI + k0 + q * 8;
  bf16x8 xf0 = *(const bf16x8*)(xrow);
  bf16x8 xf1 = *(const bf16x8*)(xrow + 32);

#pragma unroll 1
  for (int t = 0; t < NS; ++t) {
    // ---- loader waves 6,7: poll + stage h_{t-1} ----
    if (w >= 6) {
      const int lh = w - 6;  // stages batches [lh*4, lh*4+4)
      if (t > 0) {
        const unsigned tgt = (unsigned)t;
        const unsigned* fp = flagsG + lh * 32 + (lane & 31);
        unsigned fl = __hip_atomic_load(fp, __ATOMIC_RELAXED, __HIP_MEMORY_SCOPE_AGENT);
        while (!__all((int)(fl >= tgt)))
          fl = __hip_atomic_load(fp, __ATOMIC_RELAXED, __HIP_MEMORY_SCOPE_AGENT);
        asm volatile("" ::: "memory");  // keep DMA below the poll
      }
#pragma unroll
      for (int r4 = 0; r4 < 4; ++r4) {
        const int bl = lh * 4 + r4;
        const float* srow = (t == 0)
            ? (h0 + (size_t)(g * 8 + bl) * NH)
            : (out + ((size_t)(g * 8 + bl) * NS + (t - 1)) * NH);
        __builtin_amdgcn_global_load_lds(
            (const __attribute__((address_space(1))) unsigned*)(srow + lane * 4),
            (__attribute__((address_space(3))) unsigned*)&hexL[bl][0], 16, 0, 0);
        __builtin_amdgcn_global_load_lds(
            (const __attribute__((address_space(1))) unsigned*)(srow + 256 + lane * 4),
            (__attribute__((address_space(3))) unsigned*)&hexL[bl][256], 16, 0, 0);
      }
    }

    // ---- x-path MFMA (all waves; loaders' overlaps their DMA round trip) ----
    f32x4 acc[4];
#pragma unroll
    for (int g4 = 0; g4 < 4; ++g4) acc[g4] = (f32x4){0.f, 0.f, 0.f, 0.f};
#pragma unroll
    for (int g4 = 0; g4 < 4; ++g4) {
      acc[g4] = __builtin_amdgcn_mfma_f32_16x16x32_bf16(xf0, wih_hi[g4][0], acc[g4], 0, 0, 0);
      acc[g4] = __builtin_amdgcn_mfma_f32_16x16x32_bf16(xf0, wih_lo[g4][0], acc[g4], 0, 0, 0);
      acc[g4] = __builtin_amdgcn_mfma_f32_16x16x32_bf16(xf1, wih_hi[g4][1], acc[g4], 0, 0, 0);
      acc[g4] = __builtin_amdgcn_mfma_f32_16x16x32_bf16(xf1, wih_lo[g4][1], acc[g4], 0, 0, 0);
    }
    if (w >= 6) asm volatile("s_waitcnt vmcnt(0)" ::: "memory");  // DMA landed
    __builtin_amdgcn_s_barrier();  // S1: h staged
    asm volatile("" ::: "memory");

    // ---- h-path: fp32 from LDS -> hi/lo bf16 -> 3-term MFMA ----
#pragma unroll
    for (int kc = 0; kc < 2; ++kc) {
      const float* hp = &hexL[b8][k0 + kc * 32 + q * 8];
      float4 A = *(const float4*)hp;
      float4 B = *(const float4*)(hp + 4);
      float hv8[8] = {A.x, A.y, A.z, A.w, B.x, B.y, B.z, B.w};
      bf16x8 hh, hl;
#pragma unroll
      for (int r = 0; r < 8; ++r) {
        unsigned short a = f2bf(hv8[r]);
        hh[r] = (short)a;
        hl[r] = (short)f2bf(hv8[r] - bf2f(a));
      }
#pragma unroll
      for (int g4 = 0; g4 < 4; ++g4) {
        acc[g4] = __builtin_amdgcn_mfma_f32_16x16x32_bf16(hh, whh_hi[g4][kc], acc[g4], 0, 0, 0);
        acc[g4] = __builtin_amdgcn_mfma_f32_16x16x32_bf16(hl, whh_hi[g4][kc], acc[g4], 0, 0, 0);
        acc[g4] = __builtin_amdgcn_mfma_f32_16x16x32_bf16(hh, whh_lo[g4][kc], acc[g4], 0, 0, 0);
      }
    }

#pragma unroll
    for (int g4 = 0; g4 < 4; ++g4)
#pragma unroll
      for (int r = 0; r < 4; ++r) part[g4][w][r][lane] = acc[g4][r];

    asm volatile("s_waitcnt lgkmcnt(0)" ::: "memory");
    __builtin_amdgcn_s_barrier();  // S2: part visible
    asm volatile("" ::: "memory");
    // WAR safety: hexL/part rewritten at t+1 only after loaders pass their
    // flag gate (own-slice flags require reducers below to have read part).

    const int tn = (t + 1 < NS) ? t + 1 : t;
    if (w < 2) {  // reducers: lane owns (b = w*4+q, j = c)
      float sI = bI, sF = bF, sG = bG, sO = bO;
      const int cidx = c + w * 16;
#pragma unroll
      for (int ww = 0; ww < 8; ++ww) {
        sI += part[0][ww][q][cidx];
        sF += part[1][ww][q][cidx];
        sG += part[2][ww][q][cidx];
        sO += part[3][ww][q][cidx];
      }
      float cn = sigm(sF) * cst + sigm(sI) * tanh_f(sG);
      cst = cn;
      float hv = sigm(sO) * tanh_f(cn);

      // publish: sc1 store of hv into out (the output store IS the exchange)
      unsigned* dst = (unsigned*)out + ((size_t)bgc * NS + t) * NH + jg;
      __hip_atomic_store(dst, __float_as_uint(hv), __ATOMIC_RELAXED, __HIP_MEMORY_SCOPE_AGENT);
      asm volatile("s_waitcnt vmcnt(0)" ::: "memory");  // at MALL
      if (lane == 0)
        __hip_atomic_store(flagsG + w * 32 + s, (unsigned)(t + 1),
                           __ATOMIC_RELAXED, __HIP_MEMORY_SCOPE_AGENT);

      if (t == NS - 1) {  // final h/c tail (plain; flushed at kernel end)
        size_t hoff = (size_t)NB * NS * NH;
        out[hoff + (size_t)bgc * NH + jg] = hv;
        out[hoff + (size_t)NB * NH + (size_t)bgc * NH + jg] = cn;
      }
    }
    // x prefetch for t+1 (in flight across next S1 wait)
    xf0 = *(const bf16x8*)(xrow + (size_t)tn * NI);
    xf1 = *(const bf16x8*)(xrow + (size_t)tn * NI + 32);
  }
}

extern "C" void kernel_launch(void* const* d_in, const int* in_sizes, int n_in,
                              void* d_out, int out_size, void* d_ws, size_t ws_size,
                              hipStream_t stream) {
  if (ws_size < WS_BYTES_NEEDED) return;  // fail visibly rather than corrupt

  const float* x   = (const float*)d_in[0];
  const float* h0  = (const float*)d_in[1];
  const float* c0  = (const float*)d_in[2];
  const float* Wih = (const float*)d_in[3];
  const float* bih = (const float*)d_in[4];
  const float* Whh = (const float*)d_in[5];
  const float* bhh = (const float*)d_in[6];
  float* out = (float*)d_out;
  unsigned int* ws = (unsigned int*)d_ws;
  unsigned short* xbptr = (unsigned short*)(ws + XBF_OFF);

  k_xconv<<<dim3(16384), dim3(256), 0, stream>>>(x, xbptr);
  k_init<<<dim3(2), dim3(256), 0, stream>>>(ws);

  void* args[] = {(void*)&Wih, (void*)&bih, (void*)&Whh, (void*)&bhh,
                  (void*)&h0,  (void*)&c0,  (void*)&out, (void*)&ws};
  hipLaunchCooperativeKernel((const void*)k_lstm, dim3(256), dim3(512), args, 0, stream);
}